// Round 18
// baseline (55.940 us; speedup 1.0000x reference)
//
#include <hip/hip_runtime.h>

typedef _Float16 f16x8 __attribute__((ext_vector_type(8)));
typedef float f32x4 __attribute__((ext_vector_type(4)));

__device__ __forceinline__ unsigned short f2h(float f) {
  union { _Float16 h; unsigned short u; } v;
  v.h = (_Float16)f;
  return v.u;
}
__device__ __forceinline__ f16x8 splat8(float w) {
  _Float16 h = (_Float16)w;
  f16x8 v = {h, h, h, h, h, h, h, h};
  return v;
}

// ---------------- kernel 0: merged prep (verified R14) ----------------
// bid < 1024 : x NCHW f32 -> NHWC f16 xt[b][h][w][c]
// bid >= 1024: weight f32 [O][C][9] -> FRAG-MAJOR f16 wfrag[g][kt][lane][8]
__global__ __launch_bounds__(256) void prep_wx(
    const float* __restrict__ x, const float* __restrict__ w,
    unsigned short* __restrict__ xt, uint4* __restrict__ wfrag) {
  const int bid = blockIdx.x;
  const int t = threadIdx.x;
  if (bid >= 1024) {
    const int idx = (bid - 1024) * 256 + t;  // 0..73727
    const int l = idx & 63;
    const int kt = (idx >> 6) % 72;
    const int g = idx / (72 * 64);  // 0..15
    const int o = g * 16 + (l & 15);
    const int kbase = kt * 32 + ((l >> 4) * 8);
    unsigned short h[8];
#pragma unroll
    for (int e = 0; e < 8; ++e) {
      const int klin = kbase + e;
      const int kk = klin >> 8;
      const int c = klin & 255;
      h[e] = f2h(w[((size_t)o * 256 + c) * 9 + kk]);
    }
    uint4 p;
    p.x = (unsigned)h[0] | ((unsigned)h[1] << 16);
    p.y = (unsigned)h[2] | ((unsigned)h[3] << 16);
    p.z = (unsigned)h[4] | ((unsigned)h[5] << 16);
    p.w = (unsigned)h[6] | ((unsigned)h[7] << 16);
    wfrag[idx] = p;
    return;
  }
  const int b = bid >> 8;
  const int h = (bid >> 2) & 63;
  const int cq = bid & 3;
  const int wave = t >> 6, lane = t & 63;
  __shared__ float lds[64][65];
  const int wpos = t >> 2, sub = t & 3;
  const int cl0 = wave * 4 + (lane >> 4);
  const int w0 = (lane & 15) * 4;
#pragma unroll
  for (int iter = 0; iter < 4; ++iter) {
    const int cl = iter * 16 + cl0;
    const int c = cq * 64 + cl;
    float4 v = *(const float4*)(x + (((size_t)b * 256 + c) * 64 + h) * 64 + w0);
    lds[cl][w0] = v.x; lds[cl][w0 + 1] = v.y;
    lds[cl][w0 + 2] = v.z; lds[cl][w0 + 3] = v.w;
  }
  __syncthreads();
  unsigned short hb[16];
#pragma unroll
  for (int j = 0; j < 16; ++j) hb[j] = f2h(lds[sub * 16 + j][wpos]);
  uint4 p0, p1;
  p0.x = (unsigned)hb[0] | ((unsigned)hb[1] << 16);
  p0.y = (unsigned)hb[2] | ((unsigned)hb[3] << 16);
  p0.z = (unsigned)hb[4] | ((unsigned)hb[5] << 16);
  p0.w = (unsigned)hb[6] | ((unsigned)hb[7] << 16);
  p1.x = (unsigned)hb[8] | ((unsigned)hb[9] << 16);
  p1.y = (unsigned)hb[10] | ((unsigned)hb[11] << 16);
  p1.z = (unsigned)hb[12] | ((unsigned)hb[13] << 16);
  p1.w = (unsigned)hb[14] | ((unsigned)hb[15] << 16);
  unsigned short* dst = xt + (((size_t)b * 64 + h) * 64 + wpos) * 256 + cq * 64 + sub * 16;
  *(uint4*)dst = p0;
  *(uint4*)(dst + 8) = p1;
}

// ---------------- fused: A-in-VGPR, lgkm-only barriers, 2 blocks/CU ----------
// block = (b, nt=h, mh=M-half). Out tile [128 o][64 hw]. 36 phases of K=64.
// 512 thr = 8 waves = 4m x 2n: wave owns 32 rows x 32 cols, fm=2 x fn=2 x
// 2 ksub = 8 MFMA/phase. Grid 512 -> 2 independent blocks/CU fill each
// other's barrier-jitter holes. Taps/combine duplicated across the mh pair
// (accepted: +295 MB L2, VALU has headroom).
__device__ __forceinline__ void combine8(uint4 q0, uint4 q1, uint4 q2, uint4 q3,
                                         float4 wt, _Float16* dst) {
  f16x8 t0, t1, t2, t3;
  __builtin_memcpy(&t0, &q0, 16);
  __builtin_memcpy(&t1, &q1, 16);
  __builtin_memcpy(&t2, &q2, 16);
  __builtin_memcpy(&t3, &q3, 16);
  f16x8 r = t0 * splat8(wt.x);
  r += t1 * splat8(wt.y);
  r += t2 * splat8(wt.z);
  r += t3 * splat8(wt.w);
  __builtin_memcpy(dst, &r, 16);
}

__global__ __launch_bounds__(512, 4) void dcn_fused(
    const unsigned short* __restrict__ xt, const float* __restrict__ off,
    const float* __restrict__ mask, const uint4* __restrict__ wfrag,
    const float* __restrict__ bias, float* __restrict__ out) {
  __shared__ __align__(16) _Float16 Bs[2][4096];  // 16 KB ring
  __shared__ __align__(16) float swt[9 * 64 * 4];   // 9216 B
  __shared__ __align__(16) int sidx[9 * 64 * 4];    // 9216 B

  const int bid = blockIdx.x;
  const int id = ((bid & 7) << 6) | (bid >> 3);  // bijective (512 = 8*64)
  const int b = id >> 7;
  const int nt = (id >> 1) & 63;  // h row
  const int mh = id & 1;          // M-half: rows mh*128..mh*128+127

  const int tid = threadIdx.x;
  const int lane = tid & 63;
  const int wv = tid >> 6;
  const int mg = wv & 3;    // 32-row group within the 128
  const int nh2 = wv >> 2;  // 32-col half of the 64 positions
  const int lh = lane & 15, lg = lane >> 4;

  // ---- precompute per-(pos,k) tap weights & indices (full 64 pos) ----
  for (int pair = tid; pair < 576; pair += 512) {
    const int k = pair >> 6;   // 0..8
    const int pl = pair & 63;  // = w
    float oy = off[(((size_t)b * 18 + 2 * k) * 64 + nt) * 64 + pl];
    float ox = off[(((size_t)b * 18 + 2 * k + 1) * 64 + nt) * 64 + pl];
    float m = mask[(((size_t)b * 9 + k) * 64 + nt) * 64 + pl];
    float py = oy + (float)(nt - 1 + k / 3);
    float px = ox + (float)(pl - 1 + k % 3);
    float y0f = floorf(py), x0f = floorf(px);
    float ly = py - y0f, lx = px - x0f;
    float hy = 1.f - ly, hx = 1.f - lx;
    int y0 = (int)y0f, x0 = (int)x0f;
    int y1 = y0 + 1, x1 = x0 + 1;
    bool vy0 = (y0 >= 0) && (y0 < 64);
    bool vy1 = (y1 >= 0) && (y1 < 64);
    bool vx0 = (x0 >= 0) && (x0 < 64);
    bool vx1 = (x1 >= 0) && (x1 < 64);
    int yc0 = min(max(y0, 0), 63), yc1 = min(max(y1, 0), 63);
    int xc0 = min(max(x0, 0), 63), xc1 = min(max(x1, 0), 63);
    int* sp = sidx + (k * 64 + pl) * 4;
    float* wp = swt + (k * 64 + pl) * 4;
    sp[0] = (yc0 * 64 + xc0) * 256;
    sp[1] = (yc0 * 64 + xc1) * 256;
    sp[2] = (yc1 * 64 + xc0) * 256;
    sp[3] = (yc1 * 64 + xc1) * 256;
    wp[0] = (vy0 && vx0) ? hy * hx * m : 0.f;
    wp[1] = (vy0 && vx1) ? hy * lx * m : 0.f;
    wp[2] = (vy1 && vx0) ? ly * hx * m : 0.f;
    wp[3] = (vy1 && vx1) ? ly * lx * m : 0.f;
  }

  // ---- A geometry: frag-major; wave owns row-groups mh*8+mg*2, +1 ----
  const uint4* aBase = wfrag + (size_t)(mh * 8 + mg * 2) * 4608 + lane;

  // ---- B build geometry (verified R12; all 512 threads build full B) ----
  const int pos = tid >> 3, ci = tid & 7;
  const unsigned short* xtb = xt + (size_t)b * 1048576 + ci * 8;
  const int bsw = (ci >> 2) * 2048 + pos * 32 + (((ci & 3) ^ ((pos >> 1) & 3)) * 8);

  // ---- MFMA B-fragment offsets (wave reads its 32-col half only) ----
  const int csw = (lg ^ ((lh >> 1) & 3)) * 8;
  int boff[2];
#pragma unroll
  for (int fn = 0; fn < 2; ++fn) boff[fn] = (nh2 * 32 + fn * 16 + lh) * 32 + csw;

  // AR[j]: j&1 = row-group (fm), j>>1 = k-subtile. Max idx 73727 OK.
#define LOADA(P, AR)                                                               \
  do {                                                                             \
    _Pragma("unroll") for (int j = 0; j < 4; ++j)                                  \
        AR[j] = aBase[(size_t)((((j & 1) * 72) + 2 * (P) + (j >> 1)) * 64)];       \
  } while (0)

#define LOADTAPS(Q0, Q1, Q2, Q3, IX, CO)                                           \
  do {                                                                             \
    Q0 = *(const uint4*)(xtb + (IX).x + (CO));                                     \
    Q1 = *(const uint4*)(xtb + (IX).y + (CO));                                     \
    Q2 = *(const uint4*)(xtb + (IX).z + (CO));                                     \
    Q3 = *(const uint4*)(xtb + (IX).w + (CO));                                     \
  } while (0)

#define MFMA_PHASE(BUF, AR)                                                        \
  do {                                                                             \
    const _Float16* Bb = &Bs[BUF][0];                                              \
    f16x8 b0[2], b1[2];                                                            \
    _Pragma("unroll") for (int fn = 0; fn < 2; ++fn) {                             \
      b0[fn] = *(const f16x8*)(Bb + boff[fn]);                                     \
      b1[fn] = *(const f16x8*)(Bb + 2048 + boff[fn]);                              \
    }                                                                              \
    __builtin_amdgcn_s_setprio(1);                                                 \
    _Pragma("unroll") for (int fm = 0; fm < 2; ++fm)                               \
        _Pragma("unroll") for (int fn = 0; fn < 2; ++fn) {                         \
      acc[fm][fn] = __builtin_amdgcn_mfma_f32_16x16x32_f16(                        \
          *(const f16x8*)&AR[fm], b0[fn], acc[fm][fn], 0, 0, 0);                   \
      acc[fm][fn] = __builtin_amdgcn_mfma_f32_16x16x32_f16(                        \
          *(const f16x8*)&AR[2 + fm], b1[fn], acc[fm][fn], 0, 0, 0);               \
    }                                                                              \
    __builtin_amdgcn_s_setprio(0);                                                 \
  } while (0)

#define BAR()                                                                      \
  do {                                                                             \
    asm volatile("s_waitcnt lgkmcnt(0)" ::: "memory");                             \
    __builtin_amdgcn_sched_barrier(0);                                             \
    __builtin_amdgcn_s_barrier();                                                  \
    __builtin_amdgcn_sched_barrier(0);                                             \
  } while (0)

  // phase p: A(p+1)->AL; taps(p+2)->QL; MFMA(p) from AC+Bs[p&1];
  // combine(taps p+1 = QC)->Bs[(p+1)&1]; lgkm-only barrier.
#define PHASE(P_, AL, AC, QL0, QL1, QL2, QL3, QC0, QC1, QC2, QC3)                  \
  do {                                                                             \
    LOADA((P_) + 1, AL);                                                           \
    int4 ix = *(const int4*)(sidx + ((((P_) + 2) >> 2) * 64 + pos) * 4);           \
    LOADTAPS(QL0, QL1, QL2, QL3, ix, (((P_) + 2) & 3) * 64);                       \
    float4 wt4 = *(const float4*)(swt + ((((P_) + 1) >> 2) * 64 + pos) * 4);       \
    MFMA_PHASE((P_) & 1, AC);                                                      \
    combine8(QC0, QC1, QC2, QC3, wt4, &Bs[((P_) + 1) & 1][0] + bsw);               \
    BAR();                                                                         \
  } while (0)

  f32x4 acc[2][2] = {};
  uint4 AE[4], AO[4];
  uint4 qA0, qA1, qA2, qA3, qB0, qB1, qB2, qB3;

  __syncthreads();  // swt/sidx ready

  // ---- prologue: combine tile 0 -> Bs[0]; A(0)->AE; taps(1)->qB ----
  {
    float4 wt0 = *(const float4*)(swt + pos * 4);
    int4 ix0 = *(const int4*)(sidx + pos * 4);
    LOADTAPS(qA0, qA1, qA2, qA3, ix0, 0);
    combine8(qA0, qA1, qA2, qA3, wt0, &Bs[0][0] + bsw);
    LOADA(0, AE);
    LOADTAPS(qB0, qB1, qB2, qB3, ix0, 64);
    BAR();
  }

  for (int p = 0; p < 34; p += 2) {
    PHASE(p, AO, AE, qA0, qA1, qA2, qA3, qB0, qB1, qB2, qB3);
    PHASE(p + 1, AE, AO, qB0, qB1, qB2, qB3, qA0, qA1, qA2, qA3);
  }
  // ---- tail: phase 34 (no tap prefetch), phase 35 (MFMA only) ----
  {
    LOADA(35, AO);
    float4 wt4 = *(const float4*)(swt + (8 * 64 + pos) * 4);
    MFMA_PHASE(0, AE);                                   // tile 34
    combine8(qB0, qB1, qB2, qB3, wt4, &Bs[1][0] + bsw);  // tile 35
    BAR();
    MFMA_PHASE(1, AO);                                   // tile 35
  }

  // ---- epilogue ----
  float* outb = out + (size_t)b * 1048576 + (size_t)nt * 64 + nh2 * 32;
#pragma unroll
  for (int fm = 0; fm < 2; ++fm) {
#pragma unroll
    for (int i = 0; i < 4; ++i) {
      const int o = mh * 128 + mg * 32 + fm * 16 + lg * 4 + i;
      const float bs = bias[o];
      float* orow = outb + (size_t)o * 4096 + lh;
#pragma unroll
      for (int fn = 0; fn < 2; ++fn) orow[fn * 16] = acc[fm][fn][i] + bs;
    }
  }
#undef LOADA
#undef LOADTAPS
#undef MFMA_PHASE
#undef BAR
#undef PHASE
}

extern "C" void kernel_launch(void* const* d_in, const int* in_sizes, int n_in,
                              void* d_out, int out_size, void* d_ws, size_t ws_size,
                              hipStream_t stream) {
  const float* x = (const float*)d_in[0];
  const float* off = (const float*)d_in[1];
  const float* mask = (const float*)d_in[2];
  const float* wgt = (const float*)d_in[3];
  const float* bias = (const float*)d_in[4];
  float* out = (float*)d_out;

  uint4* wfrag = (uint4*)d_ws;                              // 73728*16B = 1.18 MB
  unsigned short* xtp = (unsigned short*)(wfrag + 73728);   // 8.4 MB

  prep_wx<<<1312, 256, 0, stream>>>(x, wgt, xtp, wfrag);
  dcn_fused<<<512, 512, 0, stream>>>(xtp, off, mask, wfrag, bias, out);
}

// Round 19
// 45.689 us; speedup vs baseline: 1.2243x; 1.2243x over previous
//
#include <hip/hip_runtime.h>

typedef _Float16 f16x8 __attribute__((ext_vector_type(8)));
typedef float f32x4 __attribute__((ext_vector_type(4)));

__device__ __forceinline__ unsigned short f2h(float f) {
  union { _Float16 h; unsigned short u; } v;
  v.h = (_Float16)f;
  return v.u;
}
__device__ __forceinline__ f16x8 splat8(float w) {
  _Float16 h = (_Float16)w;
  f16x8 v = {h, h, h, h, h, h, h, h};
  return v;
}

// ---------------- kernel 0: merged prep (verified R14) ----------------
__global__ __launch_bounds__(256) void prep_wx(
    const float* __restrict__ x, const float* __restrict__ w,
    unsigned short* __restrict__ xt, uint4* __restrict__ wfrag) {
  const int bid = blockIdx.x;
  const int t = threadIdx.x;
  if (bid >= 1024) {
    const int idx = (bid - 1024) * 256 + t;  // 0..73727
    const int l = idx & 63;
    const int kt = (idx >> 6) % 72;
    const int g = idx / (72 * 64);  // 0..15
    const int o = g * 16 + (l & 15);
    const int kbase = kt * 32 + ((l >> 4) * 8);
    unsigned short h[8];
#pragma unroll
    for (int e = 0; e < 8; ++e) {
      const int klin = kbase + e;
      const int kk = klin >> 8;
      const int c = klin & 255;
      h[e] = f2h(w[((size_t)o * 256 + c) * 9 + kk]);
    }
    uint4 p;
    p.x = (unsigned)h[0] | ((unsigned)h[1] << 16);
    p.y = (unsigned)h[2] | ((unsigned)h[3] << 16);
    p.z = (unsigned)h[4] | ((unsigned)h[5] << 16);
    p.w = (unsigned)h[6] | ((unsigned)h[7] << 16);
    wfrag[idx] = p;
    return;
  }
  const int b = bid >> 8;
  const int h = (bid >> 2) & 63;
  const int cq = bid & 3;
  const int wave = t >> 6, lane = t & 63;
  __shared__ float lds[64][65];
  const int wpos = t >> 2, sub = t & 3;
  const int cl0 = wave * 4 + (lane >> 4);
  const int w0 = (lane & 15) * 4;
#pragma unroll
  for (int iter = 0; iter < 4; ++iter) {
    const int cl = iter * 16 + cl0;
    const int c = cq * 64 + cl;
    float4 v = *(const float4*)(x + (((size_t)b * 256 + c) * 64 + h) * 64 + w0);
    lds[cl][w0] = v.x; lds[cl][w0 + 1] = v.y;
    lds[cl][w0 + 2] = v.z; lds[cl][w0 + 3] = v.w;
  }
  __syncthreads();
  unsigned short hb[16];
#pragma unroll
  for (int j = 0; j < 16; ++j) hb[j] = f2h(lds[sub * 16 + j][wpos]);
  uint4 p0, p1;
  p0.x = (unsigned)hb[0] | ((unsigned)hb[1] << 16);
  p0.y = (unsigned)hb[2] | ((unsigned)hb[3] << 16);
  p0.z = (unsigned)hb[4] | ((unsigned)hb[5] << 16);
  p0.w = (unsigned)hb[6] | ((unsigned)hb[7] << 16);
  p1.x = (unsigned)hb[8] | ((unsigned)hb[9] << 16);
  p1.y = (unsigned)hb[10] | ((unsigned)hb[11] << 16);
  p1.z = (unsigned)hb[12] | ((unsigned)hb[13] << 16);
  p1.w = (unsigned)hb[14] | ((unsigned)hb[15] << 16);
  unsigned short* dst = xt + (((size_t)b * 64 + h) * 64 + wpos) * 256 + cq * 64 + sub * 16;
  *(uint4*)dst = p0;
  *(uint4*)(dst + 8) = p1;
}

// ---------------- fused: A-in-VGPR, lgkm-only barriers, 4m x 2k waves --------
// block = (b, nt=h). Out tile [256 o][64 hw]. 36 phases of K=64.
// 512 thr = 8 waves: m = wv&3 (rows m*64..+63), ks = wv>>2 (K32 half).
// Wave reads ONLY its k-half of B (frag LDS reads halved vs R14); per-phase
// MFMA = fm4 x fn4 x 1 ksub = 16 (same total). Epilogue: k-reduce via LDS.
__device__ __forceinline__ void combine8(uint4 q0, uint4 q1, uint4 q2, uint4 q3,
                                         float4 wt, _Float16* dst) {
  f16x8 t0, t1, t2, t3;
  __builtin_memcpy(&t0, &q0, 16);
  __builtin_memcpy(&t1, &q1, 16);
  __builtin_memcpy(&t2, &q2, 16);
  __builtin_memcpy(&t3, &q3, 16);
  f16x8 r = t0 * splat8(wt.x);
  r += t1 * splat8(wt.y);
  r += t2 * splat8(wt.z);
  r += t3 * splat8(wt.w);
  __builtin_memcpy(dst, &r, 16);
}

__global__ __launch_bounds__(512, 2) void dcn_fused(
    const unsigned short* __restrict__ xt, const float* __restrict__ off,
    const float* __restrict__ mask, const uint4* __restrict__ wfrag,
    const float* __restrict__ bias, float* __restrict__ out) {
  extern __shared__ char smem[];
  _Float16* Bs = (_Float16*)smem;              // [2][4096] = 16384 B
  float* swt = (float*)(smem + 16384);         // [9*64*4] = 9216 B
  int* sidx = (int*)(smem + 25600);            // [9*64*4] = 9216 B (end 34816)
  float* red = (float*)smem;                   // epilogue reuse: 256*68*4 = 69632 B

  const int bid = blockIdx.x;
  const int id = ((bid & 7) << 5) | (bid >> 3);  // XCD-contiguous, bijective
  const int b = id >> 6;
  const int nt = id & 63;  // h row

  const int tid = threadIdx.x;
  const int lane = tid & 63;
  const int wv = tid >> 6;
  const int m = wv & 3;    // rows m*64..m*64+63
  const int ks = wv >> 2;  // K32 half
  const int lh = lane & 15, lg = lane >> 4;

  // ---- precompute per-(pos,k) tap weights & indices ----
  for (int pair = tid; pair < 576; pair += 512) {
    const int k = pair >> 6;   // 0..8
    const int pl = pair & 63;  // = w
    float oy = off[(((size_t)b * 18 + 2 * k) * 64 + nt) * 64 + pl];
    float ox = off[(((size_t)b * 18 + 2 * k + 1) * 64 + nt) * 64 + pl];
    float mk = mask[(((size_t)b * 9 + k) * 64 + nt) * 64 + pl];
    float py = oy + (float)(nt - 1 + k / 3);
    float px = ox + (float)(pl - 1 + k % 3);
    float y0f = floorf(py), x0f = floorf(px);
    float ly = py - y0f, lx = px - x0f;
    float hy = 1.f - ly, hx = 1.f - lx;
    int y0 = (int)y0f, x0 = (int)x0f;
    int y1 = y0 + 1, x1 = x0 + 1;
    bool vy0 = (y0 >= 0) && (y0 < 64);
    bool vy1 = (y1 >= 0) && (y1 < 64);
    bool vx0 = (x0 >= 0) && (x0 < 64);
    bool vx1 = (x1 >= 0) && (x1 < 64);
    int yc0 = min(max(y0, 0), 63), yc1 = min(max(y1, 0), 63);
    int xc0 = min(max(x0, 0), 63), xc1 = min(max(x1, 0), 63);
    int* sp = sidx + (k * 64 + pl) * 4;
    float* wp = swt + (k * 64 + pl) * 4;
    sp[0] = (yc0 * 64 + xc0) * 256;
    sp[1] = (yc0 * 64 + xc1) * 256;
    sp[2] = (yc1 * 64 + xc0) * 256;
    sp[3] = (yc1 * 64 + xc1) * 256;
    wp[0] = (vy0 && vx0) ? hy * hx * mk : 0.f;
    wp[1] = (vy0 && vx1) ? hy * lx * mk : 0.f;
    wp[2] = (vy1 && vx0) ? ly * hx * mk : 0.f;
    wp[3] = (vy1 && vx1) ? ly * lx * mk : 0.f;
  }

  // ---- A geometry: frag-major; wave (m,ks) owns groups m*4..m*4+3, kt=2P+ks --
  const uint4* aBase = wfrag + (size_t)(m * 4) * 4608 + lane;  // 4608 = 72*64

  // ---- B build geometry (verified R12; all 512 threads build full B) ----
  const int pos = tid >> 3, ci = tid & 7;
  const unsigned short* xtb = xt + (size_t)b * 1048576 + ci * 8;
  const int bsw = (ci >> 2) * 2048 + pos * 32 + (((ci & 3) ^ ((pos >> 1) & 3)) * 8);

  // ---- MFMA B-fragment offsets (wave reads only its K32 half) ----
  const int csw = (lg ^ ((lh >> 1) & 3)) * 8;
  int boff[4];
#pragma unroll
  for (int fn = 0; fn < 4; ++fn) boff[fn] = ks * 2048 + (fn * 16 + lh) * 32 + csw;

  // AR[j] = A frag for row-group m*4+j, kt = 2P+ks. Max idx 73727 OK.
#define LOADA(P, AR)                                                               \
  do {                                                                             \
    _Pragma("unroll") for (int j = 0; j < 4; ++j)                                  \
        AR[j] = aBase[(size_t)((j * 72 + 2 * (P) + ks) * 64)];                     \
  } while (0)

#define LOADTAPS(Q0, Q1, Q2, Q3, IX, CO)                                           \
  do {                                                                             \
    Q0 = *(const uint4*)(xtb + (IX).x + (CO));                                     \
    Q1 = *(const uint4*)(xtb + (IX).y + (CO));                                     \
    Q2 = *(const uint4*)(xtb + (IX).z + (CO));                                     \
    Q3 = *(const uint4*)(xtb + (IX).w + (CO));                                     \
  } while (0)

#define MFMA_PHASE(BUF, AR)                                                        \
  do {                                                                             \
    const _Float16* Bb = Bs + (BUF) * 4096;                                        \
    f16x8 bv[4];                                                                   \
    _Pragma("unroll") for (int fn = 0; fn < 4; ++fn)                               \
        bv[fn] = *(const f16x8*)(Bb + boff[fn]);                                   \
    __builtin_amdgcn_s_setprio(1);                                                 \
    _Pragma("unroll") for (int fm = 0; fm < 4; ++fm)                               \
        _Pragma("unroll") for (int fn = 0; fn < 4; ++fn)                           \
            acc[fm][fn] = __builtin_amdgcn_mfma_f32_16x16x32_f16(                  \
                *(const f16x8*)&AR[fm], bv[fn], acc[fm][fn], 0, 0, 0);             \
    __builtin_amdgcn_s_setprio(0);                                                 \
  } while (0)

#define BAR()                                                                      \
  do {                                                                             \
    asm volatile("s_waitcnt lgkmcnt(0)" ::: "memory");                             \
    __builtin_amdgcn_sched_barrier(0);                                             \
    __builtin_amdgcn_s_barrier();                                                  \
    __builtin_amdgcn_sched_barrier(0);                                             \
  } while (0)

  // phase p: A(p+1)->AL; taps(p+2)->QL; MFMA(p) from AC+Bs[p&1];
  // combine(taps p+1 = QC)->Bs[(p+1)&1]; lgkm-only barrier.
#define PHASE(P_, AL, AC, QL0, QL1, QL2, QL3, QC0, QC1, QC2, QC3)                  \
  do {                                                                             \
    LOADA((P_) + 1, AL);                                                           \
    int4 ix = *(const int4*)(sidx + ((((P_) + 2) >> 2) * 64 + pos) * 4);           \
    LOADTAPS(QL0, QL1, QL2, QL3, ix, (((P_) + 2) & 3) * 64);                       \
    float4 wt4 = *(const float4*)(swt + ((((P_) + 1) >> 2) * 64 + pos) * 4);       \
    MFMA_PHASE((P_) & 1, AC);                                                      \
    combine8(QC0, QC1, QC2, QC3, wt4, Bs + (((P_) + 1) & 1) * 4096 + bsw);         \
    BAR();                                                                         \
  } while (0)

  f32x4 acc[4][4] = {};
  uint4 AE[4], AO[4];
  uint4 qA0, qA1, qA2, qA3, qB0, qB1, qB2, qB3;

  __syncthreads();  // swt/sidx ready

  // ---- prologue: combine tile 0 -> Bs[0]; A(0)->AE; taps(1)->qB ----
  {
    float4 wt0 = *(const float4*)(swt + pos * 4);
    int4 ix0 = *(const int4*)(sidx + pos * 4);
    LOADTAPS(qA0, qA1, qA2, qA3, ix0, 0);
    combine8(qA0, qA1, qA2, qA3, wt0, Bs + bsw);
    LOADA(0, AE);
    LOADTAPS(qB0, qB1, qB2, qB3, ix0, 64);
    BAR();
  }

  for (int p = 0; p < 34; p += 2) {
    PHASE(p, AO, AE, qA0, qA1, qA2, qA3, qB0, qB1, qB2, qB3);
    PHASE(p + 1, AE, AO, qB0, qB1, qB2, qB3, qA0, qA1, qA2, qA3);
  }
  // ---- tail: phase 34 (no tap prefetch), phase 35 (MFMA only) ----
  {
    LOADA(35, AO);
    float4 wt4 = *(const float4*)(swt + (8 * 64 + pos) * 4);
    MFMA_PHASE(0, AE);                                     // tile 34
    combine8(qB0, qB1, qB2, qB3, wt4, Bs + 4096 + bsw);    // tile 35
    BAR();
    MFMA_PHASE(1, AO);                                     // tile 35
  }

  // ---- k-reduction epilogue (red overlaps Bs/tables; all dead now) ----
  __syncthreads();
  if (ks == 1) {
#pragma unroll
    for (int fm = 0; fm < 4; ++fm)
#pragma unroll
      for (int fn = 0; fn < 4; ++fn)
#pragma unroll
        for (int i = 0; i < 4; ++i)
          red[(m * 64 + fm * 16 + lg * 4 + i) * 68 + fn * 16 + lh] = acc[fm][fn][i];
  }
  __syncthreads();
  if (ks == 0) {
    float* outb = out + (size_t)b * 1048576 + (size_t)nt * 64;
#pragma unroll
    for (int fm = 0; fm < 4; ++fm)
#pragma unroll
      for (int i = 0; i < 4; ++i) {
        const int o = m * 64 + fm * 16 + lg * 4 + i;
        const float bs = bias[o];
        float* orow = outb + (size_t)o * 4096 + lh;
        const float* rrow = red + (m * 64 + fm * 16 + lg * 4 + i) * 68 + lh;
#pragma unroll
        for (int fn = 0; fn < 4; ++fn)
          orow[fn * 16] = acc[fm][fn][i] + rrow[fn * 16] + bs;
      }
  }
#undef LOADA
#undef LOADTAPS
#undef MFMA_PHASE
#undef BAR
#undef PHASE
}

extern "C" void kernel_launch(void* const* d_in, const int* in_sizes, int n_in,
                              void* d_out, int out_size, void* d_ws, size_t ws_size,
                              hipStream_t stream) {
  const float* x = (const float*)d_in[0];
  const float* off = (const float*)d_in[1];
  const float* mask = (const float*)d_in[2];
  const float* wgt = (const float*)d_in[3];
  const float* bias = (const float*)d_in[4];
  float* out = (float*)d_out;

  uint4* wfrag = (uint4*)d_ws;                              // 73728*16B = 1.18 MB
  unsigned short* xtp = (unsigned short*)(wfrag + 73728);   // 8.4 MB

  const int smem_bytes = 69632;  // max(Bs+tables=34816, red=69632)
  (void)hipFuncSetAttribute(reinterpret_cast<const void*>(&dcn_fused),
                            hipFuncAttributeMaxDynamicSharedMemorySize, smem_bytes);

  prep_wx<<<1312, 256, 0, stream>>>(x, wgt, xtp, wfrag);
  dcn_fused<<<256, 512, smem_bytes, stream>>>(xtp, off, mask, wfrag, bias, out);
}